// Round 9
// baseline (521.211 us; speedup 1.0000x reference)
//
#include <hip/hip_runtime.h>
#include <hip/hip_bf16.h>
#include <stdint.h>

#define TTOK 8192          // B*N tokens
#define KDIM 1024
#define KHID 2048
#define NEXP 8
#define NPAIR 16384        // TTOK * top2
#define RBLK 512           // router blocks (16 tokens each)

typedef __attribute__((ext_vector_type(8))) short bf16x8;
typedef __attribute__((ext_vector_type(4))) float f32x4;

__device__ __forceinline__ unsigned short f2bf(float f) {
  union { float f; uint32_t u; } v; v.f = f;
  uint32_t r = (v.u + 0x7FFFu + ((v.u >> 16) & 1u)) >> 16;
  return (unsigned short)r;
}
__device__ __forceinline__ uint32_t pack2(float a, float b) {
  return (uint32_t)f2bf(a) | ((uint32_t)f2bf(b) << 16);
}
__device__ __forceinline__ float bf2f(unsigned short u) {
  union { uint32_t u; float f; } v; v.u = (uint32_t)u << 16; return v.f;
}

// async global->LDS, 16B per lane; LDS dest is wave-uniform base + lane*16
__device__ __forceinline__ void llds16(const void* g, void* l) {
  __builtin_amdgcn_global_load_lds(
      (const __attribute__((address_space(1))) uint32_t*)g,
      (__attribute__((address_space(3))) uint32_t*)l, 16, 0, 0);
}

__device__ __forceinline__ f32x4 MF(bf16x8 a, bf16x8 b, f32x4 c) {
  return __builtin_amdgcn_mfma_f32_16x16x32_bf16(a, b, c, 0, 0, 0);
}

// ---------------- fp32 -> bf16 conversion of w1, w3, w2 (x fused into router) ----------------
__global__ __launch_bounds__(256) void convert_kernel(
    const float4* __restrict__ w1, const float4* __restrict__ w3,
    const float4* __restrict__ w2, uint4* __restrict__ w1b,
    uint4* __restrict__ w3b, uint4* __restrict__ w2b) {
  size_t u = (size_t)blockIdx.x * 256 + threadIdx.x;   // unit = 8 floats
  const size_t NW = (size_t)NEXP * KHID * KDIM / 8;    // 2097152
  const float4* src; uint4* dst; size_t i;
  if (u < NW)               { src = w1; dst = w1b; i = u; }
  else if (u < 2 * NW)      { src = w3; dst = w3b; i = u - NW; }
  else if (u < 3 * NW)      { src = w2; dst = w2b; i = u - 2 * NW; }
  else return;
  float4 a = src[2 * i], b = src[2 * i + 1];
  uint4 r;
  r.x = pack2(a.x, a.y); r.y = pack2(a.z, a.w);
  r.z = pack2(b.x, b.y); r.w = pack2(b.z, b.w);
  dst[i] = r;
}

// ---------------- router: fp64 logits, top-2, softmax; also emits xb (bf16) ----------------
__global__ __launch_bounds__(256) void router_kernel(
    const float* __restrict__ x, const float* __restrict__ rwgt,
    float* __restrict__ dout, int* __restrict__ sel, float* __restrict__ rwt,
    int* __restrict__ lslot, int* __restrict__ blkcnt,
    unsigned short* __restrict__ xb) {
  __shared__ float rl[NEXP * KDIM];   // 32 KB
  __shared__ int lcnt[NEXP];
  for (int i = threadIdx.x; i < NEXP * KDIM / 4; i += 256)
    ((float4*)rl)[i] = ((const float4*)rwgt)[i];
  if (threadIdx.x < NEXP) lcnt[threadIdx.x] = 0;
  __syncthreads();
  int wid = threadIdx.x >> 6, lane = threadIdx.x & 63;
#pragma unroll 1
  for (int tt = 0; tt < 4; ++tt) {
    int t = blockIdx.x * 16 + wid * 4 + tt;
    const float* xt = x + (size_t)t * KDIM;
    float xf[16];
#pragma unroll
    for (int i = 0; i < 16; i++) xf[i] = xt[lane + 64 * i];
    // fused x -> bf16 (coalesced per i)
#pragma unroll
    for (int i = 0; i < 16; i++) xb[(size_t)t * KDIM + lane + 64 * i] = f2bf(xf[i]);
    double acc[NEXP] = {0, 0, 0, 0, 0, 0, 0, 0};
#pragma unroll
    for (int i = 0; i < 16; i++) {
      double xv = (double)xf[i];
      const float* rr = rl + lane + 64 * i;
#pragma unroll
      for (int e = 0; e < NEXP; e++) acc[e] += xv * (double)rr[e * KDIM];
    }
#pragma unroll
    for (int e = 0; e < NEXP; e++) {
      double a = acc[e];
#pragma unroll
      for (int off = 32; off > 0; off >>= 1) a += __shfl_xor(a, off);
      acc[e] = a;
    }
    if (lane == 0) {
      int e1 = 0; double l1 = acc[0];
#pragma unroll
      for (int e = 1; e < NEXP; e++) if (acc[e] > l1) { l1 = acc[e]; e1 = e; }
      int e2 = (e1 == 0) ? 1 : 0; double l2 = acc[e2];
#pragma unroll
      for (int e = 0; e < NEXP; e++)
        if (e != e1 && e != e2 && acc[e] > l2) { l2 = acc[e]; e2 = e; }
      double p2 = exp(l2 - l1);
      double s = 1.0 + p2;
      float wa = (float)(1.0 / s), wb = (float)(p2 / s);
      float* rw_out = dout + (size_t)TTOK * KDIM;
      float* sel_out = rw_out + (size_t)TTOK * 2;
      rw_out[2 * t] = wa;  rw_out[2 * t + 1] = wb;
      sel_out[2 * t] = (float)e1;  sel_out[2 * t + 1] = (float)e2;
      sel[2 * t] = e1;  sel[2 * t + 1] = e2;
      rwt[2 * t] = wa;  rwt[2 * t + 1] = wb;
      int s1 = atomicAdd(&lcnt[e1], 1);     // LDS atomic: block-local, fast
      int s2 = atomicAdd(&lcnt[e2], 1);
      lslot[2 * t] = s1;  lslot[2 * t + 1] = s2;
    }
  }
  __syncthreads();
  if (threadIdx.x < NEXP) blkcnt[blockIdx.x * NEXP + threadIdx.x] = lcnt[threadIdx.x];
}

// ---------------- scan: blkcnt[512][8] -> per-block bases (in place) + meta ----------------
__global__ void scan_kernel(int* __restrict__ blkcnt, int* __restrict__ meta) {
  __shared__ int csum[64];
  const int tid = threadIdx.x;          // 64 threads
  const int e = tid & 7, c = tid >> 3;  // 8 chunks x 64 blocks
  int run = 0;
#pragma unroll 1
  for (int b = c * 64; b < c * 64 + 64; ++b) {
    int v = blkcnt[b * 8 + e];
    blkcnt[b * 8 + e] = run;            // local prefix within chunk
    run += v;
  }
  csum[c * 8 + e] = run;
  __syncthreads();
  if (tid < 8) {
    int tot = 0;
#pragma unroll
    for (int cc = 0; cc < 8; ++cc) { int v = csum[cc * 8 + tid]; csum[cc * 8 + tid] = tot; tot += v; }
    meta[tid] = tot;
  }
  __syncthreads();
  if (tid == 0) {
    int o = 0;
#pragma unroll
    for (int ee = 0; ee < 8; ++ee) { meta[8 + ee] = o; o += meta[ee]; }
    meta[16] = o;
  }
  const int base = csum[c * 8 + e];
#pragma unroll 1
  for (int b = c * 64; b < c * 64 + 64; ++b) blkcnt[b * 8 + e] += base;
}

// ---------------- fill: pure gather, no atomics; also builds pair->row map ----------------
__global__ __launch_bounds__(256) void fill_kernel(
    const int* __restrict__ sel, const float* __restrict__ rwt,
    const int* __restrict__ lslot, const int* __restrict__ blkcnt,
    const int* __restrict__ meta, int* __restrict__ ptok, float* __restrict__ prw,
    int* __restrict__ irow) {
  int i = blockIdx.x * 256 + threadIdx.x;   // pair index = t*2 + k
  if (i >= NPAIR) return;
  int e = sel[i];
  int t = i >> 1;
  int blk = t >> 4;                          // 16 tokens per router block
  int row = meta[8 + e] + blkcnt[blk * 8 + e] + lslot[i];
  ptok[row] = t;
  prw[row] = rwt[i];
  irow[i] = row;                             // inverse map for combine
}

// ------ 128x128 / BK=64 / 4-wave / SINGLE-buffer 32KiB / m97-style 2-barrier GEMM ------
// Occupancy is the mechanism: 32 KiB LDS + 60 VGPR admit 5 blocks/CU; launch_bounds
// min-waves=5 requests it. Inter-block MFMA covers per-block stage/barrier drain (m114).
// G=1: hidden = silu(Xg @ w1^T) * (Xg @ w3^T); SiLU wave-local.
// G=2: pout[pairrow] = hidden @ w2^T, stored bf16 (combine applies weights in f32).
template<int G>
__device__ __forceinline__ void gemm_body(
    const unsigned short* __restrict__ A,
    const unsigned short* __restrict__ B0,
    const unsigned short* __restrict__ B1,
    const int* __restrict__ meta,
    const int* __restrict__ ptok,
    unsigned short* __restrict__ hid_out,
    unsigned short* __restrict__ pout) {
  constexpr int KK = (G == 1) ? KDIM : KHID;   // row stride
  constexpr int NT = KK / 64;                  // 16 or 32 K-tiles

  // ---- XCD chunking: HW XCD = linear%8; chunk = 8mt x 8nb (G1) / 8mt x 4nb (G2)
  //      => ~4MB L2 working set per chunk, chunk pinned to one XCD. ----
  int e, mt, nb;
  {
    int L = blockIdx.x;
    int x = L & 7, k = L >> 3;
    if (G == 1) {
      // 6144 blocks: 96 chunks of 64 (8mt x 8nb); per expert 12 chunks (3 mt-c x 4 nb-c)
      int c = (k >> 6) * 8 + x;        // 0..95
      int p = k & 63;
      e = c / 12; int cw = c % 12;
      mt = (cw % 3) * 8 + (p & 7);
      nb = (cw / 3) * 8 + (p >> 3);
    } else {
      // 1536 blocks: 48 chunks of 32 (8mt x 4nb); per expert 6 chunks (3 mt-c x 2 nb-c)
      int c = (k >> 5) * 8 + x;        // 0..47
      int p = k & 31;
      e = c / 6; int cw = c % 6;
      mt = (cw % 3) * 8 + (p & 7);
      nb = (cw / 3) * 4 + (p >> 3);
    }
  }

  const int cnt = meta[e];
  const int m0 = mt * 128;
  if (m0 >= cnt) return;
  const int off = meta[8 + e];

  __shared__ unsigned short lA[128 * 64];   // 16 KiB
  __shared__ unsigned short lB[128 * 64];   // 16 KiB

  const int tid = threadIdx.x;
  const int wid = tid >> 6, lane = tid & 63;
  const int wm = wid >> 1, wn = wid & 1;
  const int cc = lane & 15, hi = lane >> 4;

  // ---- staging sources: thread handles granules g = s*256 + wid*64 + lane, s=0..3
  //      row = g>>3 = s*32 + wid*8 + (lane>>3); col8 = lane&7, pre-swizzled by row&7 ----
  const int srow_lo = wid * 8 + (lane >> 3);         // + s*32
  const int scol = (((lane & 7) ^ ((lane >> 3) & 7)) << 3);
  const unsigned short* asrc[4];
  const unsigned short* bsrc[4];
#pragma unroll
  for (int s = 0; s < 4; ++s) {
    int row = s * 32 + srow_lo;
    int ar = m0 + row;
    if (ar > cnt - 1) ar = cnt - 1;
    if (G == 1) {
      int tok = ptok[off + ar];
      asrc[s] = A + (size_t)tok * KK + scol;
    } else {
      asrc[s] = A + (size_t)(off + ar) * KK + scol;
    }
    if (G == 1) {
      // B row r: wave-half g2=r>>6 -> cols nb*64 + g2*32 + (r&31); (r&63)<32 ? w1 : w3
      int brow = nb * 64 + (row >> 6) * 32 + (row & 31);
      const unsigned short* bb = ((row & 63) < 32) ? B0 : B1;
      bsrc[s] = bb + ((size_t)e * KHID + brow) * KK + scol;
    } else {
      bsrc[s] = B0 + ((size_t)e * KDIM + nb * 128 + row) * KK + scol;
    }
  }

  // ---- zero-conflict swizzled read offsets (R4-verified pattern) ----
  const int sw0 = ((hi) ^ (cc & 7)) << 3;            // ks=0
  const int sw1 = ((4 + hi) ^ (cc & 7)) << 3;        // ks=1

  f32x4 acc[4][4] = {};

#pragma unroll 1
  for (int kt = 0; kt < NT; ++kt) {
    // stage tile kt (A: 4 loads, B: 4 loads per thread)
#pragma unroll
    for (int s = 0; s < 4; ++s) {
      llds16(asrc[s] + kt * 64, &lA[(s * 256 + wid * 64) * 8]);
      llds16(bsrc[s] + kt * 64, &lB[(s * 256 + wid * 64) * 8]);
    }
    __syncthreads();   // compiler emits vmcnt(0) drain before barrier (m97)

    bf16x8 bfr[4][2];
#pragma unroll
    for (int nf = 0; nf < 4; ++nf) {
      const unsigned short* r = lB + (wn * 64 + nf * 16 + cc) * 64;
      bfr[nf][0] = *(const bf16x8*)(r + sw0);
      bfr[nf][1] = *(const bf16x8*)(r + sw1);
    }
#pragma unroll
    for (int mf = 0; mf < 4; ++mf) {
      const unsigned short* r = lA + (wm * 64 + mf * 16 + cc) * 64;
      bf16x8 a0 = *(const bf16x8*)(r + sw0);
      bf16x8 a1 = *(const bf16x8*)(r + sw1);
#pragma unroll
      for (int nf = 0; nf < 4; ++nf) {
        acc[mf][nf] = MF(a0, bfr[nf][0], acc[mf][nf]);
        acc[mf][nf] = MF(a1, bfr[nf][1], acc[mf][nf]);
      }
    }
    __syncthreads();   // protect lA/lB from next stage until reads done
  }

  if (G == 1) {
    // ---- epilogue: wave-local SiLU: v1 = acc[mf][cf], v3 = acc[mf][cf+2] ----
#pragma unroll
    for (int mf = 0; mf < 4; ++mf) {
      int rlb = wm * 64 + mf * 16 + hi * 4;
#pragma unroll
      for (int cf = 0; cf < 2; ++cf) {
        int col = nb * 64 + wn * 32 + cf * 16 + cc;
#pragma unroll
        for (int r = 0; r < 4; ++r) {
          int row = rlb + r;
          if (m0 + row < cnt) {
            float v1 = acc[mf][cf][r], v3 = acc[mf][cf + 2][r];
            float h = v1 / (1.0f + __expf(-v1)) * v3;
            hid_out[(size_t)(off + m0 + row) * KHID + col] = f2bf(h);
          }
        }
      }
    }
  } else {
    // ---- epilogue: bf16 stores to pair-row buffer (no atomics) ----
#pragma unroll
    for (int mf = 0; mf < 4; ++mf) {
      int rlb = wm * 64 + mf * 16 + hi * 4;
#pragma unroll
      for (int r = 0; r < 4; ++r) {
        int row = rlb + r;
        if (m0 + row < cnt) {
          unsigned short* op = pout + (size_t)(off + m0 + row) * KDIM + nb * 128 + wn * 64;
#pragma unroll
          for (int nf = 0; nf < 4; ++nf)
            op[nf * 16 + cc] = f2bf(acc[mf][nf][r]);
        }
      }
    }
  }
}

__global__ __launch_bounds__(256, 5) void gemm1_kernel(
    const unsigned short* __restrict__ A, const unsigned short* __restrict__ B0,
    const unsigned short* __restrict__ B1, const int* __restrict__ meta,
    const int* __restrict__ ptok, unsigned short* __restrict__ hid_out) {
  gemm_body<1>(A, B0, B1, meta, ptok, hid_out, nullptr);
}

__global__ __launch_bounds__(256, 5) void gemm2_kernel(
    const unsigned short* __restrict__ A, const unsigned short* __restrict__ B0,
    const int* __restrict__ meta, const int* __restrict__ ptok,
    unsigned short* __restrict__ pout) {
  gemm_body<2>(A, B0, nullptr, meta, ptok, nullptr, pout);
}

// ---------------- combine: out[t] = w1*pair[r1] + w2*pair[r2] (deterministic) ----------------
__global__ __launch_bounds__(256) void combine_kernel(
    const unsigned short* __restrict__ pairbuf, const float* __restrict__ rwt,
    const int* __restrict__ irow, float* __restrict__ out) {
  int t = blockIdx.x;
  int r1 = irow[2 * t], r2 = irow[2 * t + 1];
  float w1 = rwt[2 * t], w2 = rwt[2 * t + 1];
  const ushort4* p1 = (const ushort4*)(pairbuf + (size_t)r1 * KDIM);
  const ushort4* p2 = (const ushort4*)(pairbuf + (size_t)r2 * KDIM);
  float4* o = (float4*)(out + (size_t)t * KDIM);
  int c = threadIdx.x;               // 256 threads x 4 cols = 1024 cols
  ushort4 a = p1[c], b = p2[c];
  float4 rv;
  rv.x = w1 * bf2f(a.x) + w2 * bf2f(b.x);
  rv.y = w1 * bf2f(a.y) + w2 * bf2f(b.y);
  rv.z = w1 * bf2f(a.z) + w2 * bf2f(b.z);
  rv.w = w1 * bf2f(a.w) + w2 * bf2f(b.w);
  o[c] = rv;
}

extern "C" void kernel_launch(void* const* d_in, const int* in_sizes, int n_in,
                              void* d_out, int out_size, void* d_ws, size_t ws_size,
                              hipStream_t stream) {
  const float* x    = (const float*)d_in[0];
  const float* rwgt = (const float*)d_in[1];
  const float* w1   = (const float*)d_in[2];
  const float* w3   = (const float*)d_in[3];
  const float* w2   = (const float*)d_in[4];
  float* out = (float*)d_out;

  char* ws = (char*)d_ws;
  const size_t OFF_META = 0;
  const size_t OFF_SEL  = 512;
  const size_t OFF_RWT  = OFF_SEL  + (size_t)NPAIR * 4;
  const size_t OFF_PTOK = OFF_RWT  + (size_t)NPAIR * 4;
  const size_t OFF_PRW  = OFF_PTOK + (size_t)NPAIR * 4;
  const size_t OFF_LSL  = OFF_PRW  + (size_t)NPAIR * 4;
  const size_t OFF_BLK  = OFF_LSL  + (size_t)NPAIR * 4;
  const size_t OFF_IRW  = OFF_BLK  + (size_t)RBLK * NEXP * 4;
  const size_t OFF_XB   = OFF_IRW  + (size_t)NPAIR * 4;                 // 512-aligned
  const size_t OFF_W1B  = OFF_XB   + (size_t)TTOK * KDIM * 2;
  const size_t OFF_W3B  = OFF_W1B  + (size_t)NEXP * KHID * KDIM * 2;
  const size_t OFF_W2B  = OFF_W3B  + (size_t)NEXP * KHID * KDIM * 2;
  const size_t OFF_HID  = OFF_W2B  + (size_t)NEXP * KDIM * KHID * 2;
  const size_t END      = OFF_HID  + (size_t)(NPAIR + 256) * KHID * 2;  // ~177 MiB
  if (ws_size < END) return;  // ws too small: fail safely (visible as absmax fail)

  int*   meta = (int*)(ws + OFF_META);
  int*   sel  = (int*)(ws + OFF_SEL);
  float* rwt  = (float*)(ws + OFF_RWT);
  int*   ptok = (int*)(ws + OFF_PTOK);
  float* prw  = (float*)(ws + OFF_PRW);   // layout stability (unused)
  int*   lsl  = (int*)(ws + OFF_LSL);
  int*   blkc = (int*)(ws + OFF_BLK);
  int*   irw  = (int*)(ws + OFF_IRW);
  unsigned short* xb  = (unsigned short*)(ws + OFF_XB);
  unsigned short* w1b = (unsigned short*)(ws + OFF_W1B);
  unsigned short* w3b = (unsigned short*)(ws + OFF_W3B);
  unsigned short* w2b = (unsigned short*)(ws + OFF_W2B);
  unsigned short* hid = (unsigned short*)(ws + OFF_HID);
  // pairbuf (16384 x 1024 bf16 = 32 MiB) overlays w1b (dead after gemm1)
  unsigned short* pairbuf = (unsigned short*)(ws + OFF_W1B);

  convert_kernel<<<24576, 256, 0, stream>>>(
      (const float4*)w1, (const float4*)w3, (const float4*)w2,
      (uint4*)w1b, (uint4*)w3b, (uint4*)w2b);
  router_kernel<<<RBLK, 256, 0, stream>>>(x, rwgt, out, sel, rwt, lsl, blkc, xb);
  scan_kernel<<<1, 64, 0, stream>>>(blkc, meta);
  fill_kernel<<<NPAIR / 256, 256, 0, stream>>>(sel, rwt, lsl, blkc, meta, ptok, prw, irw);
  gemm1_kernel<<<6144, 256, 0, stream>>>(xb, w1b, w3b, meta, ptok, hid);
  gemm2_kernel<<<1536, 256, 0, stream>>>(hid, w2b, meta, ptok, pairbuf);
  combine_kernel<<<TTOK, 256, 0, stream>>>(pairbuf, rwt, irw, out);
}

// Round 10
// 381.888 us; speedup vs baseline: 1.3648x; 1.3648x over previous
//
#include <hip/hip_runtime.h>
#include <hip/hip_bf16.h>
#include <stdint.h>

#define TTOK 8192          // B*N tokens
#define KDIM 1024
#define KHID 2048
#define NEXP 8
#define NPAIR 16384        // TTOK * top2
#define RBLK 512           // router blocks (16 tokens each)

typedef __attribute__((ext_vector_type(8))) short bf16x8;
typedef __attribute__((ext_vector_type(4))) float f32x4;

__device__ __forceinline__ unsigned short f2bf(float f) {
  union { float f; uint32_t u; } v; v.f = f;
  uint32_t r = (v.u + 0x7FFFu + ((v.u >> 16) & 1u)) >> 16;
  return (unsigned short)r;
}
__device__ __forceinline__ uint32_t pack2(float a, float b) {
  return (uint32_t)f2bf(a) | ((uint32_t)f2bf(b) << 16);
}
__device__ __forceinline__ float bf2f(unsigned short u) {
  union { uint32_t u; float f; } v; v.u = (uint32_t)u << 16; return v.f;
}

// async global->LDS, 16B per lane; LDS dest is wave-uniform base + lane*16
__device__ __forceinline__ void llds16(const void* g, void* l) {
  __builtin_amdgcn_global_load_lds(
      (const __attribute__((address_space(1))) uint32_t*)g,
      (__attribute__((address_space(3))) uint32_t*)l, 16, 0, 0);
}

__device__ __forceinline__ f32x4 MF(bf16x8 a, bf16x8 b, f32x4 c) {
  return __builtin_amdgcn_mfma_f32_16x16x32_bf16(a, b, c, 0, 0, 0);
}

// ------- fused router + weight-convert: blocks [0,RBLK) route, rest convert -------
// Router (VALU/fp64-bound) overlaps the BW-bound weight conversion in one dispatch.
__global__ __launch_bounds__(256) void prep_kernel(
    const float* __restrict__ x, const float* __restrict__ rwgt,
    const float4* __restrict__ w1, const float4* __restrict__ w3,
    const float4* __restrict__ w2,
    float* __restrict__ dout, int* __restrict__ sel, float* __restrict__ rwt,
    int* __restrict__ lslot, int* __restrict__ blkcnt,
    unsigned short* __restrict__ xb,
    uint4* __restrict__ w1b, uint4* __restrict__ w3b, uint4* __restrict__ w2b) {
  __shared__ float rl[NEXP * KDIM];   // 32 KB (router blocks only touch it)
  __shared__ int lcnt[NEXP];

  if (blockIdx.x >= RBLK) {
    // ---------------- convert path: w1,w3,w2 fp32 -> bf16 ----------------
    size_t u = (size_t)(blockIdx.x - RBLK) * 256 + threadIdx.x;  // unit = 8 floats
    const size_t NW = (size_t)NEXP * KHID * KDIM / 8;            // 2097152
    const float4* src; uint4* dst; size_t i;
    if (u < NW)          { src = w1; dst = w1b; i = u; }
    else if (u < 2 * NW) { src = w3; dst = w3b; i = u - NW; }
    else if (u < 3 * NW) { src = w2; dst = w2b; i = u - 2 * NW; }
    else return;
    float4 a = src[2 * i], b = src[2 * i + 1];
    uint4 r;
    r.x = pack2(a.x, a.y); r.y = pack2(a.z, a.w);
    r.z = pack2(b.x, b.y); r.w = pack2(b.z, b.w);
    dst[i] = r;
    return;
  }

  // ---------------- router path: fp64 logits, top-2, softmax; emits xb ----------------
  for (int i = threadIdx.x; i < NEXP * KDIM / 4; i += 256)
    ((float4*)rl)[i] = ((const float4*)rwgt)[i];
  if (threadIdx.x < NEXP) lcnt[threadIdx.x] = 0;
  __syncthreads();
  int wid = threadIdx.x >> 6, lane = threadIdx.x & 63;
#pragma unroll 1
  for (int tt = 0; tt < 4; ++tt) {
    int t = blockIdx.x * 16 + wid * 4 + tt;
    const float* xt = x + (size_t)t * KDIM;
    float xf[16];
#pragma unroll
    for (int i = 0; i < 16; i++) xf[i] = xt[lane + 64 * i];
    // fused x -> bf16 (coalesced per i)
#pragma unroll
    for (int i = 0; i < 16; i++) xb[(size_t)t * KDIM + lane + 64 * i] = f2bf(xf[i]);
    double acc[NEXP] = {0, 0, 0, 0, 0, 0, 0, 0};
#pragma unroll
    for (int i = 0; i < 16; i++) {
      double xv = (double)xf[i];
      const float* rr = rl + lane + 64 * i;
#pragma unroll
      for (int e = 0; e < NEXP; e++) acc[e] += xv * (double)rr[e * KDIM];
    }
#pragma unroll
    for (int e = 0; e < NEXP; e++) {
      double a = acc[e];
#pragma unroll
      for (int off = 32; off > 0; off >>= 1) a += __shfl_xor(a, off);
      acc[e] = a;
    }
    if (lane == 0) {
      int e1 = 0; double l1 = acc[0];
#pragma unroll
      for (int e = 1; e < NEXP; e++) if (acc[e] > l1) { l1 = acc[e]; e1 = e; }
      int e2 = (e1 == 0) ? 1 : 0; double l2 = acc[e2];
#pragma unroll
      for (int e = 0; e < NEXP; e++)
        if (e != e1 && e != e2 && acc[e] > l2) { l2 = acc[e]; e2 = e; }
      double p2 = exp(l2 - l1);
      double s = 1.0 + p2;
      float wa = (float)(1.0 / s), wb = (float)(p2 / s);
      float* rw_out = dout + (size_t)TTOK * KDIM;
      float* sel_out = rw_out + (size_t)TTOK * 2;
      rw_out[2 * t] = wa;  rw_out[2 * t + 1] = wb;
      sel_out[2 * t] = (float)e1;  sel_out[2 * t + 1] = (float)e2;
      sel[2 * t] = e1;  sel[2 * t + 1] = e2;
      rwt[2 * t] = wa;  rwt[2 * t + 1] = wb;
      int s1 = atomicAdd(&lcnt[e1], 1);     // LDS atomic: block-local, fast
      int s2 = atomicAdd(&lcnt[e2], 1);
      lslot[2 * t] = s1;  lslot[2 * t + 1] = s2;
    }
  }
  __syncthreads();
  if (threadIdx.x < NEXP) blkcnt[blockIdx.x * NEXP + threadIdx.x] = lcnt[threadIdx.x];
}

// ---------------- scan: blkcnt[512][8] -> per-block bases (in place) + meta ----------------
__global__ void scan_kernel(int* __restrict__ blkcnt, int* __restrict__ meta) {
  __shared__ int csum[64];
  const int tid = threadIdx.x;          // 64 threads
  const int e = tid & 7, c = tid >> 3;  // 8 chunks x 64 blocks
  int run = 0;
#pragma unroll 1
  for (int b = c * 64; b < c * 64 + 64; ++b) {
    int v = blkcnt[b * 8 + e];
    blkcnt[b * 8 + e] = run;            // local prefix within chunk
    run += v;
  }
  csum[c * 8 + e] = run;
  __syncthreads();
  if (tid < 8) {
    int tot = 0;
#pragma unroll
    for (int cc = 0; cc < 8; ++cc) { int v = csum[cc * 8 + tid]; csum[cc * 8 + tid] = tot; tot += v; }
    meta[tid] = tot;
  }
  __syncthreads();
  if (tid == 0) {
    int o = 0;
#pragma unroll
    for (int ee = 0; ee < 8; ++ee) { meta[8 + ee] = o; o += meta[ee]; }
    meta[16] = o;
  }
  const int base = csum[c * 8 + e];
#pragma unroll 1
  for (int b = c * 64; b < c * 64 + 64; ++b) blkcnt[b * 8 + e] += base;
}

// ---------------- fill: pure gather, no atomics; also builds pair->row map ----------------
__global__ __launch_bounds__(256) void fill_kernel(
    const int* __restrict__ sel, const float* __restrict__ rwt,
    const int* __restrict__ lslot, const int* __restrict__ blkcnt,
    const int* __restrict__ meta, int* __restrict__ ptok, float* __restrict__ prw,
    int* __restrict__ irow) {
  int i = blockIdx.x * 256 + threadIdx.x;   // pair index = t*2 + k
  if (i >= NPAIR) return;
  int e = sel[i];
  int t = i >> 1;
  int blk = t >> 4;                          // 16 tokens per router block
  int row = meta[8 + e] + blkcnt[blk * 8 + e] + lslot[i];
  ptok[row] = t;
  prw[row] = rwt[i];
  irow[i] = row;                             // inverse map for combine
}

// ------ 128x128 / BK=64 / 4-wave / SINGLE-buffer 32KiB / m97-style 2-barrier GEMM ------
// R8-proven configuration: launch_bounds(256,3) -> VGPR 60, no spill, ~3+ blocks/CU;
// inter-block MFMA covers per-block stage/barrier drain (m114). Zero-conflict swizzle.
// G=1: hidden = silu(Xg @ w1^T) * (Xg @ w3^T); SiLU wave-local.
// G=2: pout[pairrow] = hidden @ w2^T, stored bf16 (combine applies weights in f32).
template<int G>
__device__ __forceinline__ void gemm_body(
    const unsigned short* __restrict__ A,
    const unsigned short* __restrict__ B0,
    const unsigned short* __restrict__ B1,
    const int* __restrict__ meta,
    const int* __restrict__ ptok,
    unsigned short* __restrict__ hid_out,
    unsigned short* __restrict__ pout) {
  constexpr int KK = (G == 1) ? KDIM : KHID;   // row stride
  constexpr int NT = KK / 64;                  // 16 or 32 K-tiles

  // ---- XCD chunking: HW XCD = linear%8; chunk = 8mt x 8nb (G1) / 8mt x 4nb (G2)
  //      => ~4MB L2 working set per chunk, chunk pinned to one XCD. ----
  int e, mt, nb;
  {
    int L = blockIdx.x;
    int x = L & 7, k = L >> 3;
    if (G == 1) {
      // 6144 blocks: 96 chunks of 64 (8mt x 8nb); per expert 12 chunks (3 mt-c x 4 nb-c)
      int c = (k >> 6) * 8 + x;        // 0..95
      int p = k & 63;
      e = c / 12; int cw = c % 12;
      mt = (cw % 3) * 8 + (p & 7);
      nb = (cw / 3) * 8 + (p >> 3);
    } else {
      // 1536 blocks: 48 chunks of 32 (8mt x 4nb); per expert 6 chunks (3 mt-c x 2 nb-c)
      int c = (k >> 5) * 8 + x;        // 0..47
      int p = k & 31;
      e = c / 6; int cw = c % 6;
      mt = (cw % 3) * 8 + (p & 7);
      nb = (cw / 3) * 4 + (p >> 3);
    }
  }

  const int cnt = meta[e];
  const int m0 = mt * 128;
  if (m0 >= cnt) return;
  const int off = meta[8 + e];

  __shared__ unsigned short lA[128 * 64];   // 16 KiB
  __shared__ unsigned short lB[128 * 64];   // 16 KiB

  const int tid = threadIdx.x;
  const int wid = tid >> 6, lane = tid & 63;
  const int wm = wid >> 1, wn = wid & 1;
  const int cc = lane & 15, hi = lane >> 4;

  // ---- staging sources: thread handles granules g = s*256 + wid*64 + lane, s=0..3
  //      row = g>>3 = s*32 + wid*8 + (lane>>3); col8 = lane&7, pre-swizzled by row&7 ----
  const int srow_lo = wid * 8 + (lane >> 3);         // + s*32
  const int scol = (((lane & 7) ^ ((lane >> 3) & 7)) << 3);
  const unsigned short* asrc[4];
  const unsigned short* bsrc[4];
#pragma unroll
  for (int s = 0; s < 4; ++s) {
    int row = s * 32 + srow_lo;
    int ar = m0 + row;
    if (ar > cnt - 1) ar = cnt - 1;
    if (G == 1) {
      int tok = ptok[off + ar];
      asrc[s] = A + (size_t)tok * KK + scol;
    } else {
      asrc[s] = A + (size_t)(off + ar) * KK + scol;
    }
    if (G == 1) {
      // B row r: wave-half g2=r>>6 -> cols nb*64 + g2*32 + (r&31); (r&63)<32 ? w1 : w3
      int brow = nb * 64 + (row >> 6) * 32 + (row & 31);
      const unsigned short* bb = ((row & 63) < 32) ? B0 : B1;
      bsrc[s] = bb + ((size_t)e * KHID + brow) * KK + scol;
    } else {
      bsrc[s] = B0 + ((size_t)e * KDIM + nb * 128 + row) * KK + scol;
    }
  }

  // ---- zero-conflict swizzled read offsets (R4-verified pattern) ----
  const int sw0 = ((hi) ^ (cc & 7)) << 3;            // ks=0
  const int sw1 = ((4 + hi) ^ (cc & 7)) << 3;        // ks=1

  f32x4 acc[4][4] = {};

#pragma unroll 1
  for (int kt = 0; kt < NT; ++kt) {
    // stage tile kt (A: 4 loads, B: 4 loads per thread)
#pragma unroll
    for (int s = 0; s < 4; ++s) {
      llds16(asrc[s] + kt * 64, &lA[(s * 256 + wid * 64) * 8]);
      llds16(bsrc[s] + kt * 64, &lB[(s * 256 + wid * 64) * 8]);
    }
    __syncthreads();   // compiler emits vmcnt(0) drain before barrier (m97)

    bf16x8 bfr[4][2];
#pragma unroll
    for (int nf = 0; nf < 4; ++nf) {
      const unsigned short* r = lB + (wn * 64 + nf * 16 + cc) * 64;
      bfr[nf][0] = *(const bf16x8*)(r + sw0);
      bfr[nf][1] = *(const bf16x8*)(r + sw1);
    }
#pragma unroll
    for (int mf = 0; mf < 4; ++mf) {
      const unsigned short* r = lA + (wm * 64 + mf * 16 + cc) * 64;
      bf16x8 a0 = *(const bf16x8*)(r + sw0);
      bf16x8 a1 = *(const bf16x8*)(r + sw1);
#pragma unroll
      for (int nf = 0; nf < 4; ++nf) {
        acc[mf][nf] = MF(a0, bfr[nf][0], acc[mf][nf]);
        acc[mf][nf] = MF(a1, bfr[nf][1], acc[mf][nf]);
      }
    }
    __syncthreads();   // protect lA/lB from next stage until reads done
  }

  if (G == 1) {
    // ---- epilogue: wave-local SiLU: v1 = acc[mf][cf], v3 = acc[mf][cf+2] ----
#pragma unroll
    for (int mf = 0; mf < 4; ++mf) {
      int rlb = wm * 64 + mf * 16 + hi * 4;
#pragma unroll
      for (int cf = 0; cf < 2; ++cf) {
        int col = nb * 64 + wn * 32 + cf * 16 + cc;
#pragma unroll
        for (int r = 0; r < 4; ++r) {
          int row = rlb + r;
          if (m0 + row < cnt) {
            float v1 = acc[mf][cf][r], v3 = acc[mf][cf + 2][r];
            float h = v1 / (1.0f + __expf(-v1)) * v3;
            hid_out[(size_t)(off + m0 + row) * KHID + col] = f2bf(h);
          }
        }
      }
    }
  } else {
    // ---- epilogue: bf16 stores to pair-row buffer (no atomics) ----
#pragma unroll
    for (int mf = 0; mf < 4; ++mf) {
      int rlb = wm * 64 + mf * 16 + hi * 4;
#pragma unroll
      for (int r = 0; r < 4; ++r) {
        int row = rlb + r;
        if (m0 + row < cnt) {
          unsigned short* op = pout + (size_t)(off + m0 + row) * KDIM + nb * 128 + wn * 64;
#pragma unroll
          for (int nf = 0; nf < 4; ++nf)
            op[nf * 16 + cc] = f2bf(acc[mf][nf][r]);
        }
      }
    }
  }
}

__global__ __launch_bounds__(256, 3) void gemm1_kernel(
    const unsigned short* __restrict__ A, const unsigned short* __restrict__ B0,
    const unsigned short* __restrict__ B1, const int* __restrict__ meta,
    const int* __restrict__ ptok, unsigned short* __restrict__ hid_out) {
  gemm_body<1>(A, B0, B1, meta, ptok, hid_out, nullptr);
}

__global__ __launch_bounds__(256, 3) void gemm2_kernel(
    const unsigned short* __restrict__ A, const unsigned short* __restrict__ B0,
    const int* __restrict__ meta, const int* __restrict__ ptok,
    unsigned short* __restrict__ pout) {
  gemm_body<2>(A, B0, nullptr, meta, ptok, nullptr, pout);
}

// ---------------- combine: out[t] = w1*pair[r1] + w2*pair[r2] (deterministic) ----------------
__global__ __launch_bounds__(256) void combine_kernel(
    const unsigned short* __restrict__ pairbuf, const float* __restrict__ rwt,
    const int* __restrict__ irow, float* __restrict__ out) {
  int t = blockIdx.x;
  int r1 = irow[2 * t], r2 = irow[2 * t + 1];
  float w1 = rwt[2 * t], w2 = rwt[2 * t + 1];
  const ushort4* p1 = (const ushort4*)(pairbuf + (size_t)r1 * KDIM);
  const ushort4* p2 = (const ushort4*)(pairbuf + (size_t)r2 * KDIM);
  float4* o = (float4*)(out + (size_t)t * KDIM);
  int c = threadIdx.x;               // 256 threads x 4 cols = 1024 cols
  ushort4 a = p1[c], b = p2[c];
  float4 rv;
  rv.x = w1 * bf2f(a.x) + w2 * bf2f(b.x);
  rv.y = w1 * bf2f(a.y) + w2 * bf2f(b.y);
  rv.z = w1 * bf2f(a.z) + w2 * bf2f(b.z);
  rv.w = w1 * bf2f(a.w) + w2 * bf2f(b.w);
  o[c] = rv;
}

extern "C" void kernel_launch(void* const* d_in, const int* in_sizes, int n_in,
                              void* d_out, int out_size, void* d_ws, size_t ws_size,
                              hipStream_t stream) {
  const float* x    = (const float*)d_in[0];
  const float* rwgt = (const float*)d_in[1];
  const float* w1   = (const float*)d_in[2];
  const float* w3   = (const float*)d_in[3];
  const float* w2   = (const float*)d_in[4];
  float* out = (float*)d_out;

  char* ws = (char*)d_ws;
  const size_t OFF_META = 0;
  const size_t OFF_SEL  = 512;
  const size_t OFF_RWT  = OFF_SEL  + (size_t)NPAIR * 4;
  const size_t OFF_PTOK = OFF_RWT  + (size_t)NPAIR * 4;
  const size_t OFF_PRW  = OFF_PTOK + (size_t)NPAIR * 4;
  const size_t OFF_LSL  = OFF_PRW  + (size_t)NPAIR * 4;
  const size_t OFF_BLK  = OFF_LSL  + (size_t)NPAIR * 4;
  const size_t OFF_IRW  = OFF_BLK  + (size_t)RBLK * NEXP * 4;
  const size_t OFF_XB   = OFF_IRW  + (size_t)NPAIR * 4;                 // 512-aligned
  const size_t OFF_W1B  = OFF_XB   + (size_t)TTOK * KDIM * 2;
  const size_t OFF_W3B  = OFF_W1B  + (size_t)NEXP * KHID * KDIM * 2;
  const size_t OFF_W2B  = OFF_W3B  + (size_t)NEXP * KHID * KDIM * 2;
  const size_t OFF_HID  = OFF_W2B  + (size_t)NEXP * KDIM * KHID * 2;
  const size_t END      = OFF_HID  + (size_t)(NPAIR + 256) * KHID * 2;  // ~177 MiB
  if (ws_size < END) return;  // ws too small: fail safely (visible as absmax fail)

  int*   meta = (int*)(ws + OFF_META);
  int*   sel  = (int*)(ws + OFF_SEL);
  float* rwt  = (float*)(ws + OFF_RWT);
  int*   ptok = (int*)(ws + OFF_PTOK);
  float* prw  = (float*)(ws + OFF_PRW);   // layout stability (unused)
  int*   lsl  = (int*)(ws + OFF_LSL);
  int*   blkc = (int*)(ws + OFF_BLK);
  int*   irw  = (int*)(ws + OFF_IRW);
  unsigned short* xb  = (unsigned short*)(ws + OFF_XB);
  unsigned short* w1b = (unsigned short*)(ws + OFF_W1B);
  unsigned short* w3b = (unsigned short*)(ws + OFF_W3B);
  unsigned short* w2b = (unsigned short*)(ws + OFF_W2B);
  unsigned short* hid = (unsigned short*)(ws + OFF_HID);
  // pairbuf (16384 x 1024 bf16 = 32 MiB) overlays w1b (dead after gemm1)
  unsigned short* pairbuf = (unsigned short*)(ws + OFF_W1B);

  prep_kernel<<<RBLK + 24576, 256, 0, stream>>>(
      x, rwgt, (const float4*)w1, (const float4*)w3, (const float4*)w2,
      out, sel, rwt, lsl, blkc, xb, (uint4*)w1b, (uint4*)w3b, (uint4*)w2b);
  scan_kernel<<<1, 64, 0, stream>>>(blkc, meta);
  fill_kernel<<<NPAIR / 256, 256, 0, stream>>>(sel, rwt, lsl, blkc, meta, ptok, prw, irw);
  gemm1_kernel<<<6144, 256, 0, stream>>>(xb, w1b, w3b, meta, ptok, hid);
  gemm2_kernel<<<1536, 256, 0, stream>>>(hid, w2b, meta, ptok, pairbuf);
  combine_kernel<<<TTOK, 256, 0, stream>>>(pairbuf, rwt, irw, out);
}

// Round 11
// 329.744 us; speedup vs baseline: 1.5807x; 1.1581x over previous
//
#include <hip/hip_runtime.h>
#include <hip/hip_bf16.h>
#include <stdint.h>

#define TTOK 8192          // B*N tokens
#define KDIM 1024
#define KHID 2048
#define NEXP 8
#define NPAIR 16384        // TTOK * top2
#define RBLK 512           // router blocks (16 tokens each)
#define G1GRID 6144        // gemm1 compute blocks (w2-convert blocks appended after)
#define W2CVT 3072         // appended w2-convert blocks in gemm1

typedef __attribute__((ext_vector_type(8))) short bf16x8;
typedef __attribute__((ext_vector_type(4))) float f32x4;

__device__ __forceinline__ unsigned short f2bf(float f) {
  union { float f; uint32_t u; } v; v.f = f;
  uint32_t r = (v.u + 0x7FFFu + ((v.u >> 16) & 1u)) >> 16;
  return (unsigned short)r;
}
__device__ __forceinline__ uint32_t pack2(float a, float b) {
  return (uint32_t)f2bf(a) | ((uint32_t)f2bf(b) << 16);
}
__device__ __forceinline__ float bf2f(unsigned short u) {
  union { uint32_t u; float f; } v; v.u = (uint32_t)u << 16; return v.f;
}

// async global->LDS, 16B per lane; LDS dest is wave-uniform base + lane*16
__device__ __forceinline__ void llds16(const void* g, void* l) {
  __builtin_amdgcn_global_load_lds(
      (const __attribute__((address_space(1))) uint32_t*)g,
      (__attribute__((address_space(3))) uint32_t*)l, 16, 0, 0);
}

__device__ __forceinline__ f32x4 MF(bf16x8 a, bf16x8 b, f32x4 c) {
  return __builtin_amdgcn_mfma_f32_16x16x32_bf16(a, b, c, 0, 0, 0);
}

// ---------------- fp32 -> bf16 conversion of w1, w3 (w2 fused into gemm1 grid) ----------------
__global__ __launch_bounds__(256) void convert_kernel(
    const float4* __restrict__ w1, const float4* __restrict__ w3,
    uint4* __restrict__ w1b, uint4* __restrict__ w3b) {
  size_t u = (size_t)blockIdx.x * 256 + threadIdx.x;   // unit = 8 floats
  const size_t NW = (size_t)NEXP * KHID * KDIM / 8;    // 2097152
  const float4* src; uint4* dst; size_t i;
  if (u < NW)          { src = w1; dst = w1b; i = u; }
  else if (u < 2 * NW) { src = w3; dst = w3b; i = u - NW; }
  else return;
  float4 a = src[2 * i], b = src[2 * i + 1];
  uint4 r;
  r.x = pack2(a.x, a.y); r.y = pack2(a.z, a.w);
  r.z = pack2(b.x, b.y); r.w = pack2(b.z, b.w);
  dst[i] = r;
}

// ---------------- router: fp64 logits, top-2, softmax; emits xb (bf16); no global atomics ----------------
__global__ __launch_bounds__(256) void router_kernel(
    const float* __restrict__ x, const float* __restrict__ rwgt,
    float* __restrict__ dout, int* __restrict__ sel, float* __restrict__ rwt,
    int* __restrict__ lslot, int* __restrict__ blkcnt,
    unsigned short* __restrict__ xb) {
  __shared__ float rl[NEXP * KDIM];   // 32 KB
  __shared__ int lcnt[NEXP];
  for (int i = threadIdx.x; i < NEXP * KDIM / 4; i += 256)
    ((float4*)rl)[i] = ((const float4*)rwgt)[i];
  if (threadIdx.x < NEXP) lcnt[threadIdx.x] = 0;
  __syncthreads();
  int wid = threadIdx.x >> 6, lane = threadIdx.x & 63;
#pragma unroll 1
  for (int tt = 0; tt < 4; ++tt) {
    int t = blockIdx.x * 16 + wid * 4 + tt;
    const float* xt = x + (size_t)t * KDIM;
    float xf[16];
#pragma unroll
    for (int i = 0; i < 16; i++) xf[i] = xt[lane + 64 * i];
    // fused x -> bf16 (coalesced per i)
#pragma unroll
    for (int i = 0; i < 16; i++) xb[(size_t)t * KDIM + lane + 64 * i] = f2bf(xf[i]);
    double acc[NEXP] = {0, 0, 0, 0, 0, 0, 0, 0};
#pragma unroll
    for (int i = 0; i < 16; i++) {
      double xv = (double)xf[i];
      const float* rr = rl + lane + 64 * i;
#pragma unroll
      for (int e = 0; e < NEXP; e++) acc[e] += xv * (double)rr[e * KDIM];
    }
#pragma unroll
    for (int e = 0; e < NEXP; e++) {
      double a = acc[e];
#pragma unroll
      for (int off = 32; off > 0; off >>= 1) a += __shfl_xor(a, off);
      acc[e] = a;
    }
    if (lane == 0) {
      int e1 = 0; double l1 = acc[0];
#pragma unroll
      for (int e = 1; e < NEXP; e++) if (acc[e] > l1) { l1 = acc[e]; e1 = e; }
      int e2 = (e1 == 0) ? 1 : 0; double l2 = acc[e2];
#pragma unroll
      for (int e = 0; e < NEXP; e++)
        if (e != e1 && e != e2 && acc[e] > l2) { l2 = acc[e]; e2 = e; }
      double p2 = exp(l2 - l1);
      double s = 1.0 + p2;
      float wa = (float)(1.0 / s), wb = (float)(p2 / s);
      float* rw_out = dout + (size_t)TTOK * KDIM;
      float* sel_out = rw_out + (size_t)TTOK * 2;
      rw_out[2 * t] = wa;  rw_out[2 * t + 1] = wb;
      sel_out[2 * t] = (float)e1;  sel_out[2 * t + 1] = (float)e2;
      sel[2 * t] = e1;  sel[2 * t + 1] = e2;
      rwt[2 * t] = wa;  rwt[2 * t + 1] = wb;
      int s1 = atomicAdd(&lcnt[e1], 1);     // LDS atomic: block-local, fast
      int s2 = atomicAdd(&lcnt[e2], 1);
      lslot[2 * t] = s1;  lslot[2 * t + 1] = s2;
    }
  }
  __syncthreads();
  if (threadIdx.x < NEXP) blkcnt[blockIdx.x * NEXP + threadIdx.x] = lcnt[threadIdx.x];
}

// ---------------- scan: blkcnt[512][8] -> per-block bases (in place) + meta ----------------
__global__ void scan_kernel(int* __restrict__ blkcnt, int* __restrict__ meta) {
  __shared__ int csum[64];
  const int tid = threadIdx.x;          // 64 threads
  const int e = tid & 7, c = tid >> 3;  // 8 chunks x 64 blocks
  int run = 0;
#pragma unroll 1
  for (int b = c * 64; b < c * 64 + 64; ++b) {
    int v = blkcnt[b * 8 + e];
    blkcnt[b * 8 + e] = run;            // local prefix within chunk
    run += v;
  }
  csum[c * 8 + e] = run;
  __syncthreads();
  if (tid < 8) {
    int tot = 0;
#pragma unroll
    for (int cc = 0; cc < 8; ++cc) { int v = csum[cc * 8 + tid]; csum[cc * 8 + tid] = tot; tot += v; }
    meta[tid] = tot;
  }
  __syncthreads();
  if (tid == 0) {
    int o = 0;
#pragma unroll
    for (int ee = 0; ee < 8; ++ee) { meta[8 + ee] = o; o += meta[ee]; }
    meta[16] = o;
  }
  const int base = csum[c * 8 + e];
#pragma unroll 1
  for (int b = c * 64; b < c * 64 + 64; ++b) blkcnt[b * 8 + e] += base;
}

// ---------------- fill: pure gather, no atomics; also builds pair->row map ----------------
__global__ __launch_bounds__(256) void fill_kernel(
    const int* __restrict__ sel, const float* __restrict__ rwt,
    const int* __restrict__ lslot, const int* __restrict__ blkcnt,
    const int* __restrict__ meta, int* __restrict__ ptok, float* __restrict__ prw,
    int* __restrict__ irow) {
  int i = blockIdx.x * 256 + threadIdx.x;   // pair index = t*2 + k
  if (i >= NPAIR) return;
  int e = sel[i];
  int t = i >> 1;
  int blk = t >> 4;                          // 16 tokens per router block
  int row = meta[8 + e] + blkcnt[blk * 8 + e] + lslot[i];
  ptok[row] = t;
  prw[row] = rwt[i];
  irow[i] = row;                             // inverse map for combine
}

// ------ 128x128 / BK=64 / 4-wave / SINGLE-buffer 32KiB / m97-style 2-barrier GEMM ------
// R8-proven loop. launch_bounds(256,4): VGPR cap 128 >= 60 used (no spill), 4 blocks/CU.
// G=1: hidden = silu(Xg @ w1^T) * (Xg @ w3^T); SiLU wave-local.
// G=2: pout[pairrow] = hidden @ w2^T, stored bf16 (combine applies weights in f32).
template<int G>
__device__ __forceinline__ void gemm_body(
    const unsigned short* __restrict__ A,
    const unsigned short* __restrict__ B0,
    const unsigned short* __restrict__ B1,
    const int* __restrict__ meta,
    const int* __restrict__ ptok,
    unsigned short* __restrict__ hid_out,
    unsigned short* __restrict__ pout) {
  constexpr int KK = (G == 1) ? KDIM : KHID;   // row stride
  constexpr int NT = KK / 64;                  // 16 or 32 K-tiles

  // ---- XCD chunking: HW XCD = linear%8; chunk = 8mt x 8nb (G1) / 8mt x 4nb (G2)
  //      => ~4MB L2 working set per chunk, chunk pinned to one XCD. ----
  int e, mt, nb;
  {
    int L = blockIdx.x;
    int x = L & 7, k = L >> 3;
    if (G == 1) {
      // 6144 blocks: 96 chunks of 64 (8mt x 8nb); per expert 12 chunks (3 mt-c x 4 nb-c)
      int c = (k >> 6) * 8 + x;        // 0..95
      int p = k & 63;
      e = c / 12; int cw = c % 12;
      mt = (cw % 3) * 8 + (p & 7);
      nb = (cw / 3) * 8 + (p >> 3);
    } else {
      // 1536 blocks: 48 chunks of 32 (8mt x 4nb); per expert 6 chunks (3 mt-c x 2 nb-c)
      int c = (k >> 5) * 8 + x;        // 0..47
      int p = k & 31;
      e = c / 6; int cw = c % 6;
      mt = (cw % 3) * 8 + (p & 7);
      nb = (cw / 3) * 4 + (p >> 3);
    }
  }

  const int cnt = meta[e];
  const int m0 = mt * 128;
  if (m0 >= cnt) return;
  const int off = meta[8 + e];

  __shared__ unsigned short lA[128 * 64];   // 16 KiB
  __shared__ unsigned short lB[128 * 64];   // 16 KiB

  const int tid = threadIdx.x;
  const int wid = tid >> 6, lane = tid & 63;
  const int wm = wid >> 1, wn = wid & 1;
  const int cc = lane & 15, hi = lane >> 4;

  // ---- staging sources: thread handles granules g = s*256 + wid*64 + lane, s=0..3
  //      row = g>>3 = s*32 + wid*8 + (lane>>3); col8 = lane&7, pre-swizzled by row&7 ----
  const int srow_lo = wid * 8 + (lane >> 3);         // + s*32
  const int scol = (((lane & 7) ^ ((lane >> 3) & 7)) << 3);
  const unsigned short* asrc[4];
  const unsigned short* bsrc[4];
#pragma unroll
  for (int s = 0; s < 4; ++s) {
    int row = s * 32 + srow_lo;
    int ar = m0 + row;
    if (ar > cnt - 1) ar = cnt - 1;
    if (G == 1) {
      int tok = ptok[off + ar];
      asrc[s] = A + (size_t)tok * KK + scol;
    } else {
      asrc[s] = A + (size_t)(off + ar) * KK + scol;
    }
    if (G == 1) {
      // B row r: wave-half g2=r>>6 -> cols nb*64 + g2*32 + (r&31); (r&63)<32 ? w1 : w3
      int brow = nb * 64 + (row >> 6) * 32 + (row & 31);
      const unsigned short* bb = ((row & 63) < 32) ? B0 : B1;
      bsrc[s] = bb + ((size_t)e * KHID + brow) * KK + scol;
    } else {
      bsrc[s] = B0 + ((size_t)e * KDIM + nb * 128 + row) * KK + scol;
    }
  }

  // ---- zero-conflict swizzled read offsets (R4-verified pattern) ----
  const int sw0 = ((hi) ^ (cc & 7)) << 3;            // ks=0
  const int sw1 = ((4 + hi) ^ (cc & 7)) << 3;        // ks=1

  f32x4 acc[4][4] = {};

#pragma unroll 1
  for (int kt = 0; kt < NT; ++kt) {
    // stage tile kt (A: 4 loads, B: 4 loads per thread)
#pragma unroll
    for (int s = 0; s < 4; ++s) {
      llds16(asrc[s] + kt * 64, &lA[(s * 256 + wid * 64) * 8]);
      llds16(bsrc[s] + kt * 64, &lB[(s * 256 + wid * 64) * 8]);
    }
    __syncthreads();   // compiler emits vmcnt(0) drain before barrier (m97)

    bf16x8 bfr[4][2];
#pragma unroll
    for (int nf = 0; nf < 4; ++nf) {
      const unsigned short* r = lB + (wn * 64 + nf * 16 + cc) * 64;
      bfr[nf][0] = *(const bf16x8*)(r + sw0);
      bfr[nf][1] = *(const bf16x8*)(r + sw1);
    }
#pragma unroll
    for (int mf = 0; mf < 4; ++mf) {
      const unsigned short* r = lA + (wm * 64 + mf * 16 + cc) * 64;
      bf16x8 a0 = *(const bf16x8*)(r + sw0);
      bf16x8 a1 = *(const bf16x8*)(r + sw1);
#pragma unroll
      for (int nf = 0; nf < 4; ++nf) {
        acc[mf][nf] = MF(a0, bfr[nf][0], acc[mf][nf]);
        acc[mf][nf] = MF(a1, bfr[nf][1], acc[mf][nf]);
      }
    }
    __syncthreads();   // protect lA/lB from next stage until reads done
  }

  if (G == 1) {
    // ---- epilogue: wave-local SiLU: v1 = acc[mf][cf], v3 = acc[mf][cf+2] ----
#pragma unroll
    for (int mf = 0; mf < 4; ++mf) {
      int rlb = wm * 64 + mf * 16 + hi * 4;
#pragma unroll
      for (int cf = 0; cf < 2; ++cf) {
        int col = nb * 64 + wn * 32 + cf * 16 + cc;
#pragma unroll
        for (int r = 0; r < 4; ++r) {
          int row = rlb + r;
          if (m0 + row < cnt) {
            float v1 = acc[mf][cf][r], v3 = acc[mf][cf + 2][r];
            float h = v1 / (1.0f + __expf(-v1)) * v3;
            hid_out[(size_t)(off + m0 + row) * KHID + col] = f2bf(h);
          }
        }
      }
    }
  } else {
    // ---- epilogue: bf16 stores to pair-row buffer (no atomics) ----
#pragma unroll
    for (int mf = 0; mf < 4; ++mf) {
      int rlb = wm * 64 + mf * 16 + hi * 4;
#pragma unroll
      for (int r = 0; r < 4; ++r) {
        int row = rlb + r;
        if (m0 + row < cnt) {
          unsigned short* op = pout + (size_t)(off + m0 + row) * KDIM + nb * 128 + wn * 64;
#pragma unroll
          for (int nf = 0; nf < 4; ++nf)
            op[nf * 16 + cc] = f2bf(acc[mf][nf][r]);
        }
      }
    }
  }
}

// gemm1 + appended w2-convert blocks (blockIdx >= G1GRID). Safe: gemm1 blocks never
// read w2b; gemm2 (the consumer) launches after gemm1 completes. w2's 144MB of HBM
// traffic hides under gemm1's idle BW (~80% free).
__global__ __launch_bounds__(256, 4) void gemm1_kernel(
    const unsigned short* __restrict__ A, const unsigned short* __restrict__ B0,
    const unsigned short* __restrict__ B1, const int* __restrict__ meta,
    const int* __restrict__ ptok, unsigned short* __restrict__ hid_out,
    const float4* __restrict__ w2, uint4* __restrict__ w2b) {
  if (blockIdx.x >= G1GRID) {
    const size_t NW = (size_t)NEXP * KDIM * KHID / 8;   // 2097152 units of 8 floats
    const size_t STR = (size_t)W2CVT * 256;
    for (size_t u = (size_t)(blockIdx.x - G1GRID) * 256 + threadIdx.x; u < NW; u += STR) {
      float4 a = w2[2 * u], b = w2[2 * u + 1];
      uint4 r;
      r.x = pack2(a.x, a.y); r.y = pack2(a.z, a.w);
      r.z = pack2(b.x, b.y); r.w = pack2(b.z, b.w);
      w2b[u] = r;
    }
    return;
  }
  gemm_body<1>(A, B0, B1, meta, ptok, hid_out, nullptr);
}

__global__ __launch_bounds__(256, 4) void gemm2_kernel(
    const unsigned short* __restrict__ A, const unsigned short* __restrict__ B0,
    const int* __restrict__ meta, const int* __restrict__ ptok,
    unsigned short* __restrict__ pout) {
  gemm_body<2>(A, B0, nullptr, meta, ptok, nullptr, pout);
}

// ---------------- combine: out[t] = w1*pair[r1] + w2*pair[r2] (deterministic) ----------------
__global__ __launch_bounds__(256) void combine_kernel(
    const unsigned short* __restrict__ pairbuf, const float* __restrict__ rwt,
    const int* __restrict__ irow, float* __restrict__ out) {
  int t = blockIdx.x;
  int r1 = irow[2 * t], r2 = irow[2 * t + 1];
  float w1 = rwt[2 * t], w2 = rwt[2 * t + 1];
  const ushort4* p1 = (const ushort4*)(pairbuf + (size_t)r1 * KDIM);
  const ushort4* p2 = (const ushort4*)(pairbuf + (size_t)r2 * KDIM);
  float4* o = (float4*)(out + (size_t)t * KDIM);
  int c = threadIdx.x;               // 256 threads x 4 cols = 1024 cols
  ushort4 a = p1[c], b = p2[c];
  float4 rv;
  rv.x = w1 * bf2f(a.x) + w2 * bf2f(b.x);
  rv.y = w1 * bf2f(a.y) + w2 * bf2f(b.y);
  rv.z = w1 * bf2f(a.z) + w2 * bf2f(b.z);
  rv.w = w1 * bf2f(a.w) + w2 * bf2f(b.w);
  o[c] = rv;
}

extern "C" void kernel_launch(void* const* d_in, const int* in_sizes, int n_in,
                              void* d_out, int out_size, void* d_ws, size_t ws_size,
                              hipStream_t stream) {
  const float* x    = (const float*)d_in[0];
  const float* rwgt = (const float*)d_in[1];
  const float* w1   = (const float*)d_in[2];
  const float* w3   = (const float*)d_in[3];
  const float* w2   = (const float*)d_in[4];
  float* out = (float*)d_out;

  char* ws = (char*)d_ws;
  const size_t OFF_META = 0;
  const size_t OFF_SEL  = 512;
  const size_t OFF_RWT  = OFF_SEL  + (size_t)NPAIR * 4;
  const size_t OFF_PTOK = OFF_RWT  + (size_t)NPAIR * 4;
  const size_t OFF_PRW  = OFF_PTOK + (size_t)NPAIR * 4;
  const size_t OFF_LSL  = OFF_PRW  + (size_t)NPAIR * 4;
  const size_t OFF_BLK  = OFF_LSL  + (size_t)NPAIR * 4;
  const size_t OFF_IRW  = OFF_BLK  + (size_t)RBLK * NEXP * 4;
  const size_t OFF_XB   = OFF_IRW  + (size_t)NPAIR * 4;                 // 512-aligned
  const size_t OFF_W1B  = OFF_XB   + (size_t)TTOK * KDIM * 2;
  const size_t OFF_W3B  = OFF_W1B  + (size_t)NEXP * KHID * KDIM * 2;
  const size_t OFF_W2B  = OFF_W3B  + (size_t)NEXP * KHID * KDIM * 2;
  const size_t OFF_HID  = OFF_W2B  + (size_t)NEXP * KDIM * KHID * 2;
  const size_t END      = OFF_HID  + (size_t)(NPAIR + 256) * KHID * 2;  // ~177 MiB
  if (ws_size < END) return;  // ws too small: fail safely (visible as absmax fail)

  int*   meta = (int*)(ws + OFF_META);
  int*   sel  = (int*)(ws + OFF_SEL);
  float* rwt  = (float*)(ws + OFF_RWT);
  int*   ptok = (int*)(ws + OFF_PTOK);
  float* prw  = (float*)(ws + OFF_PRW);   // layout stability (unused)
  int*   lsl  = (int*)(ws + OFF_LSL);
  int*   blkc = (int*)(ws + OFF_BLK);
  int*   irw  = (int*)(ws + OFF_IRW);
  unsigned short* xb  = (unsigned short*)(ws + OFF_XB);
  unsigned short* w1b = (unsigned short*)(ws + OFF_W1B);
  unsigned short* w3b = (unsigned short*)(ws + OFF_W3B);
  unsigned short* w2b = (unsigned short*)(ws + OFF_W2B);
  unsigned short* hid = (unsigned short*)(ws + OFF_HID);
  // pairbuf (16384 x 1024 bf16 = 32 MiB) overlays w1b (dead after gemm1)
  unsigned short* pairbuf = (unsigned short*)(ws + OFF_W1B);

  convert_kernel<<<16384, 256, 0, stream>>>(
      (const float4*)w1, (const float4*)w3, (uint4*)w1b, (uint4*)w3b);
  router_kernel<<<RBLK, 256, 0, stream>>>(x, rwgt, out, sel, rwt, lsl, blkc, xb);
  scan_kernel<<<1, 64, 0, stream>>>(blkc, meta);
  fill_kernel<<<NPAIR / 256, 256, 0, stream>>>(sel, rwt, lsl, blkc, meta, ptok, prw, irw);
  gemm1_kernel<<<G1GRID + W2CVT, 256, 0, stream>>>(
      xb, w1b, w3b, meta, ptok, hid, (const float4*)w2, (uint4*)w2b);
  gemm2_kernel<<<1536, 256, 0, stream>>>(hid, w2b, meta, ptok, pairbuf);
  combine_kernel<<<TTOK, 256, 0, stream>>>(pairbuf, rwt, irw, out);
}